// Round 3
// baseline (317.203 us; speedup 1.0000x reference)
//
#include <hip/hip_runtime.h>

#define B  4
#define C  64
#define C8 8
#define DD 16
#define H  64
#define W  64
#define EPSV 1e-5f
// k = int(0.6*64) = 38 -> threshold = 38th largest = ascending index 26

__device__ __forceinline__ float silu_f(float v) {
    return v * (1.f / (1.f + __expf(-v)));
}

// ---------------- Kernel A: hh = SiLU(BN2(pw1(x) + b1)) for every location,
// stored channel-last: hht[loc*8 + o]. Reads x coalesced (float2/lane).
__global__ __launch_bounds__(256) void pw_hh_kernel(
    const float* __restrict__ x,
    const float* __restrict__ w1, const float* __restrict__ b1,
    const float* __restrict__ g2, const float* __restrict__ be2,
    const float* __restrict__ mu2, const float* __restrict__ va2,
    float* __restrict__ hht)
{
    const int gid = blockIdx.x * 256 + threadIdx.x;  // handles locations 2*gid, 2*gid+1
    const int loc = gid * 2;
    const int b = loc >> 16;
    const int r = loc & 65535;
    const float* xp = x + (long)b * (C * 65536) + r;

    float s0[C8], s1[C8];
#pragma unroll
    for (int o = 0; o < C8; ++o) { s0[o] = 0.f; s1[o] = 0.f; }
#pragma unroll
    for (int c = 0; c < C; ++c) {
        const float2 xv = *(const float2*)(xp + (long)c * 65536);
#pragma unroll
        for (int o = 0; o < C8; ++o) {
            const float wv = w1[o * C + c];      // thread-uniform -> scalar load
            s0[o] += wv * xv.x;
            s1[o] += wv * xv.y;
        }
    }
    float out0[C8], out1[C8];
#pragma unroll
    for (int o = 0; o < C8; ++o) {
        const float sc = g2[o] * rsqrtf(va2[o] + EPSV);
        out0[o] = silu_f((s0[o] + b1[o] - mu2[o]) * sc + be2[o]);
        out1[o] = silu_f((s1[o] + b1[o] - mu2[o]) * sc + be2[o]);
    }
    float4* op = (float4*)(hht + (long)loc * 8);   // 16 contiguous floats
    op[0] = make_float4(out0[0], out0[1], out0[2], out0[3]);
    op[1] = make_float4(out0[4], out0[5], out0[6], out0[7]);
    op[2] = make_float4(out1[0], out1[1], out1[2], out1[3]);
    op[3] = make_float4(out1[4], out1[5], out1[6], out1[7]);
}

// ---------------- Kernel B: depthwise 5x5 conv + BN1 + SiLU -> y1t CHANNEL-LAST
// y1t[loc*64 + c].  Block = (b, d, 8-row band), 512 threads = (c, w-octet).
// All 64 channels of a location produced inside one block (same XCD/L2 ->
// partial-line writes merge).
__global__ __launch_bounds__(512) void dwconv_kernel(
    const float* __restrict__ x, const float* __restrict__ w_dw,
    const float* __restrict__ g1, const float* __restrict__ be1,
    const float* __restrict__ mu1, const float* __restrict__ va1,
    float* __restrict__ y1t)
{
    const int blk = blockIdx.x;            // 512 blocks: b*128 + d*8 + hb
    const int hb = blk & 7;
    const int d = (blk >> 3) & 15;
    const int b = blk >> 7;
    const int c  = threadIdx.x >> 3;       // 0..63
    const int w8 = (threadIdx.x & 7) * 8;  // output cols w8..w8+7

    float wk[25];
#pragma unroll
    for (int i = 0; i < 25; ++i) wk[i] = w_dw[c * 25 + i];
    const float scale = g1[c] * rsqrtf(va1[c] + EPSV);
    const float shift = be1[c] - mu1[c] * scale;

    const long xbase = ((long)(b * C + c) * DD + d) * (H * W);
    const int  bd    = (b * DD + d) * (H * W);     // location base for y1t
    const int  hbase = hb * 8;
    const int  q     = w8 >> 2;

#pragma unroll
    for (int g = 0; g < 2; ++g) {          // two groups of 4 output rows
        float acc[4][8];
#pragma unroll
        for (int i = 0; i < 4; ++i)
#pragma unroll
            for (int ow = 0; ow < 8; ++ow) acc[i][ow] = 0.f;

#pragma unroll
        for (int j = 0; j < 8; ++j) {      // input row r = hbase + g*4 + j - 2
            const int r = hbase + g * 4 + j - 2;
            if (r >= 0 && r < H) {
                const float4* rowp = (const float4*)(x + xbase + r * W);
                const float4 z = make_float4(0.f, 0.f, 0.f, 0.f);
                float4 v0 = (w8 > 0)  ? rowp[q - 1] : z;
                float4 v1 = rowp[q];
                float4 v2 = rowp[q + 1];
                float4 v3 = (w8 < 56) ? rowp[q + 2] : z;
                float vals[16] = {v0.x, v0.y, v0.z, v0.w,
                                  v1.x, v1.y, v1.z, v1.w,
                                  v2.x, v2.y, v2.z, v2.w,
                                  v3.x, v3.y, v3.z, v3.w};
#pragma unroll
                for (int i = 0; i < 4; ++i) {
                    if (i <= j && (j - i) <= 4) {
                        const int kr = j - i;
#pragma unroll
                        for (int dw = 0; dw < 5; ++dw) {
                            const float kw = wk[kr * 5 + dw];
#pragma unroll
                            for (int ow = 0; ow < 8; ++ow)
                                acc[i][ow] += kw * vals[ow + dw + 2];
                        }
                    }
                }
            }
        }
#pragma unroll
        for (int i = 0; i < 4; ++i) {
            const int h = hbase + g * 4 + i;
            float* dst = y1t + ((long)(bd + h * W + w8)) * 64 + c;
#pragma unroll
            for (int ow = 0; ow < 8; ++ow)
                dst[ow * 64] = silu_f(acc[i][ow] * scale + shift);
        }
    }
}

// ---------------- Kernel C: y2 = pw2(hh)+b2, attn = y1t*y2, bitonic top-k,
// epilogue out = x + alpha*attn*mask.  One thread per location.
// HAVE_HH=1: hh read from hht (channel-last). HAVE_HH=0: pw1 computed here.
template<int HAVE_HH>
__global__ __launch_bounds__(256) void fuse_kernel(
    const float* __restrict__ x, const float* __restrict__ y1t,
    const float* __restrict__ hht,
    const float* __restrict__ w1, const float* __restrict__ b1,
    const float* __restrict__ g2, const float* __restrict__ be2,
    const float* __restrict__ mu2, const float* __restrict__ va2,
    const float* __restrict__ w2, const float* __restrict__ b2,
    const float* __restrict__ alphap, float* __restrict__ out)
{
    const int gid = blockIdx.x * 256 + threadIdx.x;  // one thread = one location
    const int b = gid >> 16;
    const int r = gid & 65535;
    const float* xp = x + (long)b * (C * 65536) + r;
    const float* y1p = y1t + (long)gid * 64;         // 64 contiguous floats

    float hh[C8];
    if (HAVE_HH) {
        const float4* hp = (const float4*)(hht + (long)gid * 8);
        const float4 h0 = hp[0], h1 = hp[1];
        hh[0] = h0.x; hh[1] = h0.y; hh[2] = h0.z; hh[3] = h0.w;
        hh[4] = h1.x; hh[5] = h1.y; hh[6] = h1.z; hh[7] = h1.w;
    } else {
        float s1[C8];
#pragma unroll
        for (int o = 0; o < C8; ++o) s1[o] = 0.f;
#pragma unroll
        for (int c = 0; c < C; ++c) {
            const float xc = xp[(long)c * 65536];
#pragma unroll
            for (int o = 0; o < C8; ++o) s1[o] += w1[o * C + c] * xc;
        }
#pragma unroll
        for (int o = 0; o < C8; ++o) {
            const float sc = g2[o] * rsqrtf(va2[o] + EPSV);
            hh[o] = silu_f((s1[o] + b1[o] - mu2[o]) * sc + be2[o]);
        }
    }

    // attn -> t[] (destroyed by sort; recomputed identically in epilogue)
    float t[C];
#pragma unroll
    for (int q4 = 0; q4 < 16; ++q4) {
        const float4 yv = ((const float4*)y1p)[q4];
        const float yy[4] = {yv.x, yv.y, yv.z, yv.w};
#pragma unroll
        for (int s = 0; s < 4; ++s) {
            const int c = q4 * 4 + s;
            float y2 = b2[c];
#pragma unroll
            for (int o = 0; o < C8; ++o) y2 += w2[c * C8 + o] * hh[o];
            t[c] = yy[s] * y2;
        }
    }

    // in-register bitonic sort (ascending) of 64 values
#pragma unroll
    for (int k = 2; k <= 64; k <<= 1) {
#pragma unroll
        for (int j = k >> 1; j > 0; j >>= 1) {
#pragma unroll
            for (int i = 0; i < 64; ++i) {
                const int l = i ^ j;
                if (l > i) {
                    const float u = t[i], v = t[l];
                    const float mn = fminf(u, v), mx = fmaxf(u, v);
                    if ((i & k) == 0) { t[i] = mn; t[l] = mx; }
                    else              { t[i] = mx; t[l] = mn; }
                }
            }
        }
    }
    const float thr = t[26];          // 38th largest of 64
    const float alpha = alphap[0];
    float* op = out + (long)b * (C * 65536) + r;

    // epilogue: recompute attn (same arithmetic), mask, add x
#pragma unroll
    for (int q4 = 0; q4 < 16; ++q4) {
        const float4 yv = ((const float4*)y1p)[q4];   // L1-hot re-read
        const float yy[4] = {yv.x, yv.y, yv.z, yv.w};
#pragma unroll
        for (int s = 0; s < 4; ++s) {
            const int c = q4 * 4 + s;
            float y2 = b2[c];
#pragma unroll
            for (int o = 0; o < C8; ++o) y2 += w2[c * C8 + o] * hh[o];
            const float av = yy[s] * y2;
            const float xc = xp[(long)c * 65536];
            op[(long)c * 65536] = xc + ((av >= thr) ? alpha * av : 0.f);
        }
    }
}

extern "C" void kernel_launch(void* const* d_in, const int* in_sizes, int n_in,
                              void* d_out, int out_size, void* d_ws, size_t ws_size,
                              hipStream_t stream) {
    const float* x    = (const float*)d_in[0];
    const float* w_dw = (const float*)d_in[1];
    const float* g1   = (const float*)d_in[2];
    const float* be1  = (const float*)d_in[3];
    const float* mu1  = (const float*)d_in[4];
    const float* va1  = (const float*)d_in[5];
    const float* w1   = (const float*)d_in[6];
    const float* b1   = (const float*)d_in[7];
    const float* g2   = (const float*)d_in[8];
    const float* be2  = (const float*)d_in[9];
    const float* mu2  = (const float*)d_in[10];
    const float* va2  = (const float*)d_in[11];
    const float* w2   = (const float*)d_in[12];
    const float* b2   = (const float*)d_in[13];
    const float* alp  = (const float*)d_in[14];
    float* out = (float*)d_out;

    const size_t y1_bytes = (size_t)B * C * DD * H * W * 4;   // 16.78 MB
    const size_t hh_bytes = (size_t)B * C8 * DD * H * W * 4;  //  8.39 MB
    float* y1t = (float*)d_ws;
    float* hht = (float*)((char*)d_ws + y1_bytes);
    const bool have_hh = ws_size >= y1_bytes + hh_bytes;

    dwconv_kernel<<<B * DD * 8, 512, 0, stream>>>(x, w_dw, g1, be1, mu1, va1, y1t);
    if (have_hh) {
        pw_hh_kernel<<<(B * DD * H * W) / 512, 256, 0, stream>>>(
            x, w1, b1, g2, be2, mu2, va2, hht);
        fuse_kernel<1><<<(B * DD * H * W) / 256, 256, 0, stream>>>(
            x, y1t, hht, w1, b1, g2, be2, mu2, va2, w2, b2, alp, out);
    } else {
        fuse_kernel<0><<<(B * DD * H * W) / 256, 256, 0, stream>>>(
            x, y1t, hht, w1, b1, g2, be2, mu2, va2, w2, b2, alp, out);
    }
}

// Round 4
// 226.656 us; speedup vs baseline: 1.3995x; 1.3995x over previous
//
#include <hip/hip_runtime.h>

#define C  64
#define C8 8
#define EPSV 1e-5f
// k = int(0.6*64) = 38 -> threshold = 38th largest = ascending index 26

__device__ __forceinline__ float silu_f(float v) {
    return v * (1.f / (1.f + __expf(-v)));
}

// One block = (b, d, 4-row h-band). Phase 1: depthwise 5x5 conv + BN1 + SiLU
// for all 64 channels of the band's 256 locations -> LDS (swizzled, 64 KB).
// Phase 2: thread-per-location pw1+BN2+SiLU+pw2, attn, bitonic top-k, epilogue.
__global__ __launch_bounds__(256) void fused_kernel(
    const float* __restrict__ x, const float* __restrict__ w_dw,
    const float* __restrict__ g1, const float* __restrict__ be1,
    const float* __restrict__ mu1, const float* __restrict__ va1,
    const float* __restrict__ w1, const float* __restrict__ b1,
    const float* __restrict__ g2, const float* __restrict__ be2,
    const float* __restrict__ mu2, const float* __restrict__ va2,
    const float* __restrict__ w2, const float* __restrict__ b2,
    const float* __restrict__ alphap, float* __restrict__ out)
{
    // [loc][c] with XOR-ish swizzle: idx = loc*64 + ((c+loc)&63)
    // write lanes (c, w16): bank = (c + 16*wq + A) & 63 mod 32 -> 2-way (free)
    // read  lanes (loc):    bank = (c + loc) & 63 mod 32      -> 2-way (free)
    __shared__ float y1s[64 * 256];   // 64 KB

    const int blk = blockIdx.x;        // 1024 = b*256 + d*16 + hb
    const int hb = blk & 15;
    const int d  = (blk >> 4) & 15;
    const int b  = blk >> 8;
    const int h0 = hb * 4;
    const int tid = threadIdx.x;

    // ---------------- phase 1: depthwise conv, rows h0..h0+3
    {
        const int c   = tid >> 2;          // 0..63
        const int w16 = (tid & 3) * 16;    // output cols w16..w16+15
        const int q   = w16 >> 2;

        float wk[25];
#pragma unroll
        for (int i = 0; i < 25; ++i) wk[i] = w_dw[c * 25 + i];
        const float scale = g1[c] * rsqrtf(va1[c] + EPSV);
        const float shift = be1[c] - mu1[c] * scale;
        const long xbase = ((long)(b * C + c) * 16 + d) * 4096;

        float acc[4][16];
#pragma unroll
        for (int i = 0; i < 4; ++i)
#pragma unroll
            for (int ow = 0; ow < 16; ++ow) acc[i][ow] = 0.f;

#pragma unroll
        for (int j = 0; j < 8; ++j) {      // input row r = h0 + j - 2
            const int r = h0 + j - 2;      // block-uniform guard
            if (r >= 0 && r < 64) {
                const float4* rowp = (const float4*)(x + xbase + r * 64);
                const float4 z = make_float4(0.f, 0.f, 0.f, 0.f);
                float4 u0 = (q > 0)  ? rowp[q - 1] : z;
                float4 u1 = rowp[q];
                float4 u2 = rowp[q + 1];
                float4 u3 = rowp[q + 2];
                float4 u4 = rowp[q + 3];
                float4 u5 = (q < 12) ? rowp[q + 4] : z;
                // vals[v] = x[row r, col w16 - 4 + v]
                float vals[24] = {u0.x,u0.y,u0.z,u0.w, u1.x,u1.y,u1.z,u1.w,
                                  u2.x,u2.y,u2.z,u2.w, u3.x,u3.y,u3.z,u3.w,
                                  u4.x,u4.y,u4.z,u4.w, u5.x,u5.y,u5.z,u5.w};
#pragma unroll
                for (int i = 0; i < 4; ++i) {
                    if (i <= j && (j - i) <= 4) {   // kernel row kr = j - i
                        const int kr = j - i;
#pragma unroll
                        for (int kc = 0; kc < 5; ++kc) {
                            const float kw = wk[kr * 5 + kc];
#pragma unroll
                            for (int ow = 0; ow < 16; ++ow)
                                acc[i][ow] += kw * vals[ow + kc + 2];
                        }
                    }
                }
            }
        }
#pragma unroll
        for (int i = 0; i < 4; ++i)
#pragma unroll
            for (int ow = 0; ow < 16; ++ow) {
                const int loc = i * 64 + w16 + ow;
                y1s[loc * 64 + ((c + loc) & 63)] =
                    silu_f(acc[i][ow] * scale + shift);
            }
    }
    __syncthreads();

    // ---------------- phase 2: pw1 + BN2 + SiLU + pw2, attn, top-k, epilogue
    {
        const int loc = tid;               // row = tid>>6, w = tid&63
        const int h = h0 + (tid >> 6);
        const int rg = d * 4096 + h * 64 + (tid & 63);
        const float* xp = x + (long)b * (C * 65536) + rg;

        // pw1 (x lines are L2-hot: phase 1 of this block just read them)
        float s1[C8];
#pragma unroll
        for (int o = 0; o < C8; ++o) s1[o] = 0.f;
#pragma unroll
        for (int c = 0; c < C; ++c) {
            const float xc = xp[(long)c * 65536];
#pragma unroll
            for (int o = 0; o < C8; ++o) s1[o] += w1[o * C + c] * xc;
        }
        float hh[C8];
#pragma unroll
        for (int o = 0; o < C8; ++o) {
            const float sc = g2[o] * rsqrtf(va2[o] + EPSV);
            hh[o] = silu_f((s1[o] + b1[o] - mu2[o]) * sc + be2[o]);
        }

        // attn: keep a[] for the epilogue, t[] is destroyed by the sort
        float a[C], t[C];
#pragma unroll
        for (int c = 0; c < C; ++c) {
            const float y1v = y1s[loc * 64 + ((c + loc) & 63)];
            float y2 = b2[c];
#pragma unroll
            for (int o = 0; o < C8; ++o) y2 += w2[c * C8 + o] * hh[o];
            const float av = y1v * y2;
            a[c] = av;
            t[c] = av;
        }

        // in-register bitonic sort (ascending) of 64 values
#pragma unroll
        for (int k = 2; k <= 64; k <<= 1) {
#pragma unroll
            for (int j = k >> 1; j > 0; j >>= 1) {
#pragma unroll
                for (int i = 0; i < 64; ++i) {
                    const int l = i ^ j;
                    if (l > i) {
                        const float u = t[i], v = t[l];
                        const float mn = fminf(u, v), mx = fmaxf(u, v);
                        if ((i & k) == 0) { t[i] = mn; t[l] = mx; }
                        else              { t[i] = mx; t[l] = mn; }
                    }
                }
            }
        }
        const float thr = t[26];          // 38th largest of 64
        const float alpha = alphap[0];
        float* op = out + (long)b * (C * 65536) + rg;

#pragma unroll
        for (int c = 0; c < C; ++c) {
            const float xc = xp[(long)c * 65536];   // L2-hot re-read
            const float av = a[c];
            op[(long)c * 65536] = xc + ((av >= thr) ? alpha * av : 0.f);
        }
    }
}

extern "C" void kernel_launch(void* const* d_in, const int* in_sizes, int n_in,
                              void* d_out, int out_size, void* d_ws, size_t ws_size,
                              hipStream_t stream) {
    const float* x    = (const float*)d_in[0];
    const float* w_dw = (const float*)d_in[1];
    const float* g1   = (const float*)d_in[2];
    const float* be1  = (const float*)d_in[3];
    const float* mu1  = (const float*)d_in[4];
    const float* va1  = (const float*)d_in[5];
    const float* w1   = (const float*)d_in[6];
    const float* b1   = (const float*)d_in[7];
    const float* g2   = (const float*)d_in[8];
    const float* be2  = (const float*)d_in[9];
    const float* mu2  = (const float*)d_in[10];
    const float* va2  = (const float*)d_in[11];
    const float* w2   = (const float*)d_in[12];
    const float* b2   = (const float*)d_in[13];
    const float* alp  = (const float*)d_in[14];
    float* out = (float*)d_out;

    // grid: b(4) x d(16) x h-band(16) = 1024 blocks
    fused_kernel<<<1024, 256, 0, stream>>>(
        x, w_dw, g1, be1, mu1, va1, w1, b1, g2, be2, mu2, va2, w2, b2, alp, out);
}